// Round 14
// baseline (362.056 us; speedup 1.0000x reference)
//
#include <hip/hip_runtime.h>

#define BB 2048
#define SS 200
#define VV 50257
#define EE 60
#define HH 30
#define EMBD 20
#define XD 80
#define G4 120
#define NCHUNK 50       /* 1024-col groups (k_vsum) */
#define VPAD 51200
#define VPAD2 51264     /* +64 pad rows for vwrite lookahead tile */

#define O_COV ((size_t)BB*VV)
#define O_H   (O_COV + (size_t)BB*SS)
#define O_C   (O_H + (size_t)BB*HH)
#define O_NA  (O_C + (size_t)BB*HH)
#define O_LOSS (O_NA + (size_t)BB*SS)

typedef __attribute__((ext_vector_type(8))) short short8v;
typedef __attribute__((ext_vector_type(4))) float f32x4;

__device__ __forceinline__ float sigf(float x){ return 1.f/(1.f+__expf(-x)); }

__device__ __forceinline__ short f2bf(float f){
  union { __bf16 h; short s; } u; u.h = (__bf16)f; return u.s;
}

__device__ __forceinline__ float bsum(float v, float* red, int tid){
  #pragma unroll
  for (int off=32; off; off>>=1) v += __shfl_xor(v, off);
  __syncthreads();
  if ((tid&63)==0) red[tid>>6]=v;
  __syncthreads();
  return red[0]+red[1]+red[2]+red[3];
}
__device__ __forceinline__ float bmax(float v, float* red, int tid){
  #pragma unroll
  for (int off=32; off; off>>=1) v = fmaxf(v, __shfl_xor(v, off));
  __syncthreads();
  if ((tid&63)==0) red[tid>>6]=v;
  __syncthreads();
  return fmaxf(fmaxf(red[0],red[1]),fmaxf(red[2],red[3]));
}

// ---- pack v_w -> bf16 [VPAD2][32] (k & row zero-padded), v_b -> f32 [VPAD2] ----
__global__ __launch_bounds__(256) void k_pack(
  const float* __restrict__ v_w, const float* __restrict__ v_b,
  short* __restrict__ vw_bf, float* __restrict__ vb_pad)
{
  const int idx = blockIdx.x*256 + threadIdx.x;   // VPAD2*4 quarter-rows exactly
  const int col = idx>>2, q = idx&3;
  union { short8v v; short s[8]; } u;
  #pragma unroll
  for (int j=0;j<8;j++){
    int k = q*8+j;
    u.s[j] = (col<VV && k<HH) ? f2bf(v_w[(size_t)col*HH+k]) : (short)0;
  }
  ((short8v*)vw_bf)[idx] = u.v;
  if (q==0) vb_pad[col] = (col<VV) ? v_b[col] : -1e30f;
}

// One block per batch row: context einsum + LSTM + attention energy + softmax
// + coverage, from a single LDS-staged copy of enc_out[b]. Also emits packed h.
__global__ __launch_bounds__(256) void k_row(
  const float* __restrict__ coverage, const float* __restrict__ enc_out,
  const float* __restrict__ h0, const float* __restrict__ c0,
  const float* __restrict__ attn, const int* __restrict__ dec_input,
  const float* __restrict__ embedding,
  const float* __restrict__ w_ih, const float* __restrict__ w_hh,
  const float* __restrict__ b_ih, const float* __restrict__ b_hh,
  const float* __restrict__ attn_wh_w, const float* __restrict__ attn_wh_b,
  const float* __restrict__ attn_ws_w, const float* __restrict__ attn_ws_b,
  const float* __restrict__ attn_wc, const float* __restrict__ attn_v,
  const float* __restrict__ whv, const float* __restrict__ wsv, const float* __restrict__ wxv,
  float* __restrict__ out, float* __restrict__ pgen_ws,
  float* __restrict__ losspart_ws, short* __restrict__ h_bf)
{
  const int b = blockIdx.x, tid = threadIdx.x;
  __shared__ float enc[SS*61];
  __shared__ float wT[EE*32];
  __shared__ float attn_s[SS], cov_s[SS];
  __shared__ float xls[XD], hls[HH], wsapp[HH], wc_s[HH], v_s[HH], gls[G4];
  __shared__ float ctxp[EE*4];
  __shared__ float red[4];

  {
    const float4* ep = (const float4*)(enc_out + (size_t)b*(SS*EE));
    #pragma unroll
    for (int it=0; it<12; ++it){
      int i = tid + it*256;
      if (i < (SS*EE/4)) {
        float4 v = ep[i];
        int s = i/15, e4 = (i - s*15)*4;
        float* d = &enc[s*61+e4];
        d[0]=v.x; d[1]=v.y; d[2]=v.z; d[3]=v.w;
      }
    }
  }
  if (tid < SS) { attn_s[tid]=attn[(size_t)b*SS+tid]; cov_s[tid]=coverage[(size_t)b*SS+tid]; }
  for (int i=tid; i<EE*HH; i+=256){ int h=i/EE, e=i-h*EE; wT[e*32+h]=attn_wh_w[i]; }
  if (tid >= 256-HH) { int h = tid-(256-HH); wc_s[h]=attn_wc[h]; v_s[h]=attn_v[h]; }
  __syncthreads();

  if (tid < 240){
    int g = tid/60, e = tid - g*60;
    float acc=0.f;
    for (int s=g; s<SS; s+=4) acc += attn_s[s]*enc[s*61+e];
    ctxp[e*4+g]=acc;
  }
  __syncthreads();
  if (tid < EE) xls[tid]=ctxp[tid*4]+ctxp[tid*4+1]+ctxp[tid*4+2]+ctxp[tid*4+3];
  else if (tid < EE+EMBD){
    int k = tid-EE;
    int dix = dec_input[b];
    xls[tid] = embedding[(size_t)dix*EMBD+k];
  }
  __syncthreads();

  if (tid < G4){
    float acc = b_ih[tid]+b_hh[tid];
    const float* wi = w_ih + tid*XD;
    #pragma unroll
    for (int k=0;k<XD;k++) acc += xls[k]*wi[k];
    const float* whh = w_hh + tid*HH;
    const float* h0b = h0 + (size_t)b*HH;
    #pragma unroll
    for (int k=0;k<HH;k++) acc += h0b[k]*whh[k];
    gls[tid]=acc;
  }
  __syncthreads();
  if (tid < HH){
    float c = sigf(gls[tid+HH])*c0[(size_t)b*HH+tid] + sigf(gls[tid])*tanhf(gls[tid+2*HH]);
    float h = sigf(gls[tid+3*HH])*tanhf(c);
    out[O_C+(size_t)b*HH+tid]=c;
    out[O_H+(size_t)b*HH+tid]=h;
    hls[tid]=h;
  }
  __syncthreads();
  if (tid < 4){
    union { short8v v; short s[8]; } u;
    #pragma unroll
    for (int j=0;j<8;j++){ int k=tid*8+j; u.s[j] = (k<HH)? f2bf(hls[k]) : (short)0; }
    ((short8v*)(h_bf + (size_t)b*32))[tid] = u.v;
  }
  if (tid < HH){
    float acc = attn_ws_b[tid] + attn_wh_b[tid];
    const float* w = attn_ws_w + tid*HH;
    #pragma unroll
    for (int k=0;k<HH;k++) acc += hls[k]*w[k];
    wsapp[tid]=acc;
  }
  float pv=0.f;
  if (tid<EE) pv = xls[tid]*whv[tid];
  else if (tid<EE+HH) pv = hls[tid-EE]*wsv[tid-EE];
  else if (tid<EE+HH+EMBD) pv = xls[EE+(tid-EE-HH)]*wxv[tid-EE-HH];
  float pg = sigf(bsum(pv,red,tid));
  if (tid==0) pgen_ws[b]=pg;
  __syncthreads();

  float en = -1e30f;
  if (tid < SS){
    float acc[HH];
    float cv = cov_s[tid];
    #pragma unroll
    for (int h=0;h<HH;h++) acc[h] = wsapp[h] + cv*wc_s[h];
    for (int e=0;e<EE;e++){
      float evv = enc[tid*61+e];
      #pragma unroll
      for (int h=0;h<HH;h++) acc[h] += evv*wT[e*32+h];
    }
    float e2=0.f;
    #pragma unroll
    for (int h=0;h<HH;h++) e2 += tanhf(acc[h])*v_s[h];
    en = e2;
  }
  float mx = bmax(en, red, tid);
  float ex = (tid<SS)? __expf(en-mx) : 0.f;
  float sm = bsum(ex, red, tid);
  float inv = 1.f/sm;
  float lossv = 0.f;
  if (tid<SS){
    float na = ex*inv;
    float cv = cov_s[tid];
    out[O_NA+(size_t)b*SS+tid]=na;
    out[O_COV+(size_t)b*SS+tid]=cv+na;
    lossv = fminf(na,cv);
  }
  float ls = bsum(lossv,red,tid);
  if (tid==0) losspart_ws[b]=ls;
}

// ---- vocab pass 1 (swapped MFMA, LDS-free): wave = 16 rows x 1024 cols ----
__global__ __launch_bounds__(256) void k_vsum(
  const short* __restrict__ vw_bf, const float* __restrict__ vb_pad,
  const short* __restrict__ h_bf, float* __restrict__ partial)
{
  const int tid = threadIdx.x;
  const int w = tid>>6, l = tid&63;
  const int lc = l&15, lg = l>>4;
  const int task = blockIdx.x*4 + w;          // 0..6399
  const int rg = task & 127, cg = task >> 7;  // 128 row-groups x 50 col-groups
  const int rbase = rg*16, cbase = cg*1024;

  short8v Bh = *(const short8v*)(h_bf + (size_t)(rbase+lc)*32 + lg*8);

  float ps = 0.f;
  #pragma unroll 4
  for (int t=0;t<64;t++){
    const int ct = cbase + t*16;
    short8v Av = *(const short8v*)(vw_bf + (size_t)(ct+lc)*32 + lg*8);
    f32x4 vb4 = *(const f32x4*)(vb_pad + ct + lg*4);
    f32x4 z = {0.f,0.f,0.f,0.f};
    f32x4 d = __builtin_amdgcn_mfma_f32_16x16x32_bf16(Av, Bh, z, 0,0,0);
    ps += __expf(d[0]+vb4[0]) + __expf(d[1]+vb4[1])
        + __expf(d[2]+vb4[2]) + __expf(d[3]+vb4[3]);
  }
  ps += __shfl_xor(ps,16);
  ps += __shfl_xor(ps,32);
  if (l < 16) partial[(size_t)cg*BB + rbase + lc] = ps;
}

// ---- offs[row] = log(pgen) - log(rowsum); block 8 also reduces coverage loss ----
__global__ __launch_bounds__(256) void k_off(
  const float* __restrict__ partial, const float* __restrict__ pgen,
  const float* __restrict__ lp, float* __restrict__ offs,
  float* __restrict__ lossdst)
{
  const int tid = threadIdx.x;
  if (blockIdx.x < 8){
    const int row = blockIdx.x*256 + tid;
    float s=0.f;
    #pragma unroll 5
    for (int c=0;c<NCHUNK;c++) s += partial[(size_t)c*BB + row];
    offs[row] = __logf(pgen[row]) - __logf(s);
  } else {
    __shared__ float red[4];
    float s=0.f;
    for (int i=tid;i<BB;i+=256) s+=lp[i];
    #pragma unroll
    for (int off=32; off; off>>=1) s+=__shfl_xor(s,off);
    if ((tid&63)==0) red[tid>>6]=s;
    __syncthreads();
    if (tid==0) lossdst[0]=red[0]+red[1]+red[2]+red[3];
  }
}

// ---- vocab pass 2 (swapped MFMA, register-direct, SECTOR-ALIGNED stores) ----
// Wave = 16 rows (stride 8: all share row%8 = rg&7 -> uniform misalignment
// a=(row*VV)&7 since VV%8==1) x 800 cols. Uniform shift p=(-rg)&7: each lane
// stores window [v0+p, v0+p+4) assembled from its own exp'd f4 + neighbors
// (lg+1, lg+2, one-tile lookahead for wrap) via 8 wave-uniform shfls + a
// uniform switch(p). All f4 stores 16B-aligned; each row's 64B run starts
// 32B-aligned -> FULL SECTORS ONLY (WRITE_SIZE should drop 580->~415MB).
__global__ __launch_bounds__(256) void k_vwrite(
  const short* __restrict__ vw_bf, const float* __restrict__ vb_pad,
  const short* __restrict__ h_bf, const float* __restrict__ offs,
  float* __restrict__ out)
{
  const int tid = threadIdx.x;
  const int w = tid>>6, l = tid&63;
  const int lc = l&15, lg = l>>4;
  const int task = blockIdx.x*4 + w;          // 0..8191
  const int rg = task & 127, cg = task >> 7;  // 128 row-groups x 64 col-groups
  const int row = (rg>>3)*128 + (rg&7) + 8*lc;
  const int cbase = cg*800;
  const int p = (8 - (rg&7)) & 7;             // uniform shift (VV%8==1)

  short8v Bh = *(const short8v*)(h_bf + (size_t)row*32 + lg*8);
  const float off = offs[row];
  float* orow = out + (size_t)row*VV;

  // compute_o(t): exp'd f4 for cols [cbase+16t+4lg, +4)
  #define COMPUTE_O(dst, t) {                                            \
    const int ct_ = cbase + (t)*16;                                      \
    const int v0_ = ct_ + lg*4;                                          \
    short8v Av_ = *(const short8v*)(vw_bf + (size_t)(ct_+lc)*32 + lg*8); \
    f32x4 vb4_ = *(const f32x4*)(vb_pad + v0_);                          \
    f32x4 z_ = {0.f,0.f,0.f,0.f};                                        \
    f32x4 d_ = __builtin_amdgcn_mfma_f32_16x16x32_bf16(Av_, Bh, z_, 0,0,0); \
    dst[0]=__expf(d_[0]+vb4_[0]+off); dst[1]=__expf(d_[1]+vb4_[1]+off);  \
    dst[2]=__expf(d_[2]+vb4_[2]+off); dst[3]=__expf(d_[3]+vb4_[3]+off); }

  f32x4 cur; COMPUTE_O(cur, 0);

  // row head [0,p): only cg==0, from tile 0's unshifted values
  if (cg==0 && p){
    #pragma unroll
    for (int j=0;j<4;j++){
      const int col = 4*lg + j;
      if (col < p) orow[col] = cur[j];
    }
  }

  const int s1 = (l+16)&63, s2 = (l+32)&63;
  for (int t=0;t<50;t++){
    f32x4 nx; COMPUTE_O(nx, t+1);
    f32x4 o;
    if (p == 0){
      o = cur;
    } else {
      f32x4 A, B;
      #pragma unroll
      for (int j=0;j<4;j++){
        float a1 = __shfl(cur[j], s1), b1 = __shfl(nx[j], s1);
        A[j] = (lg<3)? a1 : b1;
        float a2 = __shfl(cur[j], s2), b2 = __shfl(nx[j], s2);
        B[j] = (lg<2)? a2 : b2;
      }
      switch(p){
        case 1: o[0]=cur[1]; o[1]=cur[2]; o[2]=cur[3]; o[3]=A[0]; break;
        case 2: o[0]=cur[2]; o[1]=cur[3]; o[2]=A[0];   o[3]=A[1]; break;
        case 3: o[0]=cur[3]; o[1]=A[0];   o[2]=A[1];   o[3]=A[2]; break;
        case 4: o=A; break;
        case 5: o[0]=A[1];   o[1]=A[2];   o[2]=A[3];   o[3]=B[0]; break;
        case 6: o[0]=A[2];   o[1]=A[3];   o[2]=B[0];   o[3]=B[1]; break;
        default:o[0]=A[3];   o[1]=B[0];   o[2]=B[1];   o[3]=B[2]; break;
      }
    }
    const int g0 = cbase + t*16 + 4*lg + p;   // 16B-aligned (g0%4==0 by construction)
    if (g0 + 4 <= VV){
      *(f32x4*)(orow + g0) = o;
    } else {
      #pragma unroll
      for (int j=0;j<4;j++) if (g0 + j < VV) orow[g0+j] = o[j];
    }
    cur = nx;
  }
  #undef COMPUTE_O
}

// ---- scatter: numpy last-wins .at[rows, enc_inputs].set(new_attn), fused as += ----
__global__ __launch_bounds__(256) void k_scatter(
  const int* __restrict__ enc_inputs, const float* __restrict__ pgen,
  const float* __restrict__ na, float* __restrict__ out)
{
  __shared__ int idx_s[SS];
  const int b=blockIdx.x, tid=threadIdx.x;
  if (tid<SS) idx_s[tid]=enc_inputs[(size_t)b*SS+tid];
  __syncthreads();
  if (tid<SS){
    int idx=idx_s[tid];
    bool last=true;
    for (int s2=tid+1;s2<SS;s2++) if (idx_s[s2]==idx){ last=false; break; }
    if (last){
      float add=(1.f-pgen[b])*na[(size_t)b*SS+tid];
      out[(size_t)b*VV+idx]+=add;
    }
  }
}

extern "C" void kernel_launch(void* const* d_in, const int* in_sizes, int n_in,
                              void* d_out, int out_size, void* d_ws, size_t ws_size,
                              hipStream_t stream)
{
  const float* coverage =(const float*)d_in[0];
  const float* enc_out  =(const float*)d_in[1];
  const float* h0       =(const float*)d_in[2];
  const float* c0       =(const float*)d_in[3];
  const float* attn     =(const float*)d_in[4];
  const int*   dec_input=(const int*)d_in[5];
  const int*   enc_inputs=(const int*)d_in[6];
  const float* embedding=(const float*)d_in[7];
  const float* w_ih     =(const float*)d_in[8];
  const float* w_hh     =(const float*)d_in[9];
  const float* b_ih     =(const float*)d_in[10];
  const float* b_hh     =(const float*)d_in[11];
  const float* attn_wh_w=(const float*)d_in[12];
  const float* attn_wh_b=(const float*)d_in[13];
  const float* attn_ws_w=(const float*)d_in[14];
  const float* attn_ws_b=(const float*)d_in[15];
  const float* attn_wc  =(const float*)d_in[16];
  const float* attn_v   =(const float*)d_in[17];
  const float* whv      =(const float*)d_in[18];
  const float* wsv      =(const float*)d_in[19];
  const float* wxv      =(const float*)d_in[20];
  const float* v_w      =(const float*)d_in[21];
  const float* v_b      =(const float*)d_in[22];
  float* out=(float*)d_out;
  float* wsf=(float*)d_ws;
  float* pgen    = wsf;
  float* losspart= wsf + 2048;
  float* offs    = wsf + 4096;
  float* partial = wsf + 6144;
  float* vb_pad  = wsf + 6144 + (size_t)NCHUNK*BB;
  short* vw_bf   = (short*)(vb_pad + VPAD2);
  short* h_bf    = vw_bf + (size_t)VPAD2*32;

  k_pack<<<VPAD2*4/256,256,0,stream>>>(v_w,v_b,vw_bf,vb_pad);

  k_row<<<BB,256,0,stream>>>(coverage,enc_out,h0,c0,attn,dec_input,embedding,
    w_ih,w_hh,b_ih,b_hh,attn_wh_w,attn_wh_b,attn_ws_w,attn_ws_b,attn_wc,attn_v,
    whv,wsv,wxv,out,pgen,losspart,h_bf);

  k_vsum  <<<1600,256,0,stream>>>(vw_bf,vb_pad,h_bf,partial);
  k_off   <<<9,256,0,stream>>>(partial,pgen,losspart,offs,out+O_LOSS);
  k_vwrite<<<2048,256,0,stream>>>(vw_bf,vb_pad,h_bf,offs,out);
  k_scatter<<<BB,256,0,stream>>>(enc_inputs,pgen,out+O_NA,out);
}